// Round 2
// baseline (657.646 us; speedup 1.0000x reference)
//
#include <hip/hip_runtime.h>

// out = segment_sum(x, batch) — softmax over a size-1 axis == 1, so the
// linear layer (W, b) is mathematically dead and x is summed directly.
//
// R1 structure: one wave owns 64 contiguous rows. The wave's 64 batch ids are
// preloaded in ONE coalesced dword load (lane L holds batch[row0+L]); per-pair
// segment ids come from __shfl (ds_bpermute, lgkmcnt) so the hot loop's vmcnt
// pipeline contains ONLY x float4 loads — 8 KB in flight per wave (UNROLL=8
// pairs). Flush = 4 atomicAdds per lane at segment boundaries (rare, ~1.6 per
// wave) and once at the end.
//
// Timing note (R1 post-mortem of R0 counters): top-5 dispatches are all
// harness fillBuffer at ~320 us writing 2.048 GB @6.4 TB/s; segsum is below
// the 313 us cutoff => dur_us (647.5) includes a ~320 us harness poison fill.
// Kernel-side budget is ~325 us vs an ~80 us HBM roofline.

#define C 128
#define ROWS_PER_WAVE 64
#define WAVES_PER_BLOCK 4
#define BLOCK_THREADS (WAVES_PER_BLOCK * 64)
#define UNROLL 8  // row-pairs per iteration (16 rows, 8 KB loads in flight)

typedef float f4 __attribute__((ext_vector_type(4)));

__device__ __forceinline__ void flush_acc(float* __restrict__ out, int seg,
                                          int col4, f4& acc) {
    float* o = out + (size_t)seg * C + 4 * col4;
    atomicAdd(o + 0, acc.x);
    atomicAdd(o + 1, acc.y);
    atomicAdd(o + 2, acc.z);
    atomicAdd(o + 3, acc.w);
    acc = (f4){0.f, 0.f, 0.f, 0.f};
}

__global__ __launch_bounds__(BLOCK_THREADS)
void segsum_kernel(const f4* __restrict__ xv,   // x as float4: 32 per row
                   const int* __restrict__ batch,
                   float* __restrict__ out,
                   int n_rows, int n_segs) {
    const int wave = blockIdx.x * WAVES_PER_BLOCK + (threadIdx.x >> 6);
    const int lane = threadIdx.x & 63;
    const int half = lane >> 5;    // 0: even row of pair, 1: odd row
    const int col4 = lane & 31;    // float4 index within the row

    long row0 = (long)wave * ROWS_PER_WAVE;
    if (row0 >= n_rows) return;
    long row_end = row0 + ROWS_PER_WAVE;
    if (row_end > n_rows) row_end = n_rows;
    const int nrows_w = (int)(row_end - row0);   // 64 except possibly last wave

    // ---- preload this wave's batch ids: lane L holds batch[row0+L] ----
    long bidx = row0 + lane;
    if (bidx > (long)n_rows - 1) bidx = (long)n_rows - 1;
    int bval = batch[bidx];
    bval = min(max(bval, 0), n_segs - 1);   // crash-proofing vs bad ids

    f4 acc = (f4){0.f, 0.f, 0.f, 0.f};
    int cur = __shfl(bval, half);           // segment of row0+half

    const f4* base = xv + row0 * (C / 4) + col4;

    int i = 0;  // row offset within this wave's chunk
    // main: 8 pairs (16 rows) per iteration; vmcnt pipeline = x-loads only
    for (; i + 2 * UNROLL <= nrows_w; i += 2 * UNROLL) {
        f4 v[UNROLL];
#pragma unroll
        for (int j = 0; j < UNROLL; ++j)
            v[j] = __builtin_nontemporal_load(base + (long)(i + 2 * j + half) * (C / 4));
#pragma unroll
        for (int j = 0; j < UNROLL; ++j) {
            int seg = __shfl(bval, i + 2 * j + half);   // ds_bpermute, lgkmcnt
            if (seg != cur) {               // rare, exec-masked
                flush_acc(out, cur, col4, acc);
                cur = seg;
            }
            acc += v[j];
        }
    }
    // tail: single pairs (unused when nrows_w == 64)
    for (; i + 1 < nrows_w; i += 2) {
        f4 v = __builtin_nontemporal_load(base + (long)(i + half) * (C / 4));
        int seg = __shfl(bval, i + half);
        if (seg != cur) {
            flush_acc(out, cur, col4, acc);
            cur = seg;
        }
        acc += v;
    }
    // odd final row: processed by half==0 lanes only
    if (i < nrows_w) {
        int seg = __shfl(bval, i);
        if (half == 0) {
            f4 v = __builtin_nontemporal_load(base + (long)i * (C / 4));
            if (seg != cur) {
                flush_acc(out, cur, col4, acc);
                cur = seg;
            }
            acc += v;
        }
    }
    flush_acc(out, cur, col4, acc);
}

extern "C" void kernel_launch(void* const* d_in, const int* in_sizes, int n_in,
                              void* d_out, int out_size, void* d_ws, size_t ws_size,
                              hipStream_t stream) {
    const float* x     = (const float*)d_in[0];
    const int*   batch = (const int*)d_in[1];
    // d_in[2] = W, d_in[3] = b — unused: softmax over size-1 axis == 1.
    float* out = (float*)d_out;

    const int n_rows = in_sizes[0] / C;   // 1,000,000
    const int n_segs = out_size / C;      // 10,000

    // d_out is poisoned to 0xAA before every launch; atomics need zeros.
    hipMemsetAsync(d_out, 0, (size_t)out_size * sizeof(float), stream);

    const int n_waves  = (n_rows + ROWS_PER_WAVE - 1) / ROWS_PER_WAVE;
    const int n_blocks = (n_waves + WAVES_PER_BLOCK - 1) / WAVES_PER_BLOCK;

    segsum_kernel<<<n_blocks, BLOCK_THREADS, 0, stream>>>(
        (const f4*)x, batch, out, n_rows, n_segs);
}

// Round 3
// 639.064 us; speedup vs baseline: 1.0291x; 1.0291x over previous
//
#include <hip/hip_runtime.h>

// out = segment_sum(x, batch) — softmax over a size-1 axis == 1, so the
// linear layer (W, b) is mathematically dead and x is summed directly.
//
// R2 structure: batch is SORTED, so each segment is a contiguous row range.
// ONE WAVE PER SEGMENT: wave g binary-searches batch for its range [s,e)
// (~2x20 dependent L2-hit loads, amortized across 8K resident waves), then
// pure-streams its ~100 rows (2 rows per float4 instruction: lanes 0-31 even
// row, 32-63 odd row) and writes out[g] ONCE with a plain store after a
// cross-half shfl_xor combine.
//   - ZERO atomics (R1 had ~6.5M atomicAdd transactions)
//   - NO output memset dispatch (every out element fully overwritten;
//     empty segments write zeros — poison-safe)
//   - hot loop = x-loads + adds only, no branches, no shuffles
//
// Attribution status (R1 post-mortem): top-5 dispatches are harness fills
// (~320 us, 2.048 GB); segsum < 313 us; dur_us 650 = one fill + tiny-dispatch
// overhead + segsum. This round's pure-stream kernel (~90-130 us expected)
// disambiguates: if dur_us doesn't drop, the floor is harness-side.

#define C 128
#define WAVES_PER_BLOCK 4
#define BLOCK_THREADS (WAVES_PER_BLOCK * 64)
#define UNROLL 8  // row-pairs per iteration (16 rows, 8 KB loads in flight)

typedef float f4 __attribute__((ext_vector_type(4)));

__global__ __launch_bounds__(BLOCK_THREADS)
void segsum_kernel(const f4* __restrict__ xv,   // x as float4: 32 per row
                   const int* __restrict__ batch,
                   float* __restrict__ out,
                   int n_rows, int n_segs) {
    const int g = blockIdx.x * WAVES_PER_BLOCK + (threadIdx.x >> 6);
    if (g >= n_segs) return;
    const int lane = threadIdx.x & 63;
    const int half = lane >> 5;    // 0: even row of pair, 1: odd row
    const int col4 = lane & 31;    // float4 index within the row

    // ---- binary search: rows of segment g are [s, e) (batch sorted) ----
    int s;
    {
        int lo = 0, hi = n_rows;
        while (lo < hi) { int m = (lo + hi) >> 1; if (batch[m] < g) lo = m + 1; else hi = m; }
        s = lo;
    }
    int e;
    {
        int lo = s, hi = n_rows;
        while (lo < hi) { int m = (lo + hi) >> 1; if (batch[m] <= g) lo = m + 1; else hi = m; }
        e = lo;
    }

    f4 acc = (f4){0.f, 0.f, 0.f, 0.f};
    const f4* base = xv + (long)s * (C / 4) + col4;
    const int nr = e - s;

    int i = 0;
    // main: 8 pairs (16 rows) per iteration; vmcnt pipeline = x-loads only
    for (; i + 2 * UNROLL <= nr; i += 2 * UNROLL) {
        f4 v[UNROLL];
#pragma unroll
        for (int j = 0; j < UNROLL; ++j)
            v[j] = __builtin_nontemporal_load(base + (long)(i + 2 * j + half) * (C / 4));
#pragma unroll
        for (int j = 0; j < UNROLL; ++j)
            acc += v[j];
    }
    // tail: single pairs
    for (; i + 1 < nr; i += 2)
        acc += __builtin_nontemporal_load(base + (long)(i + half) * (C / 4));
    // odd final row: half==0 lanes only
    if (i < nr && half == 0)
        acc += __builtin_nontemporal_load(base + (long)i * (C / 4));

    // ---- combine halves and store once (no atomics) ----
#pragma unroll
    for (int k = 0; k < 4; ++k)
        acc[k] += __shfl_xor(acc[k], 32);
    if (half == 0)
        *(f4*)(out + (size_t)g * C + 4 * col4) = acc;
}

extern "C" void kernel_launch(void* const* d_in, const int* in_sizes, int n_in,
                              void* d_out, int out_size, void* d_ws, size_t ws_size,
                              hipStream_t stream) {
    const float* x     = (const float*)d_in[0];
    const int*   batch = (const int*)d_in[1];
    // d_in[2] = W, d_in[3] = b — unused: softmax over size-1 axis == 1.
    float* out = (float*)d_out;

    const int n_rows = in_sizes[0] / C;   // 1,000,000
    const int n_segs = out_size / C;      // 10,000

    // No memset: every output element is written exactly once by its wave.

    const int n_blocks = (n_segs + WAVES_PER_BLOCK - 1) / WAVES_PER_BLOCK;

    segsum_kernel<<<n_blocks, BLOCK_THREADS, 0, stream>>>(
        (const f4*)x, batch, out, n_rows, n_segs);
}